// Round 1
// baseline (3748.241 us; speedup 1.0000x reference)
//
#include <hip/hip_runtime.h>

// RGATNetwork: 2x RGATConv (R=4, H=4, C=32, HC=128, F_E=16) on N=50k nodes, E=800k edges.
// Pipeline per layer:
//   proj:   xw[r,n,:] = xin[n,:] @ w[r]          (LDS-tiled fp32 GEMM)
//   qk:     qn[r,n,h] = xw[r,n,:]@q[:,h]; kn likewise
//   ek:     ek[e,h]   = edge_attr[e,:] @ (le@e)[:,h]   (le@e folded to [16,4])
//   alpha:  a[e,h] = lrelu(qn[et,dst]+kn[et,src]+ek[e]); segment-max via encoded atomicMax
//   exp:    ex = exp(a - amax[dst]); segment-sum denom via atomicAdd
//   agg:    agg[dst,:] += (ex/denom)*xw[et,src,:]      (fp32 atomics, 32 lanes/edge)
//   epilogue: layer1 relu(+b1) -> hbuf; layer2 head-mean(+b3) -> d_out

#define NEG_SLOPE 0.2f
#define SOFT_EPS 1e-16f
#define PROJ_NODES 64

__device__ __forceinline__ unsigned fenc(float x) {
  unsigned u = __float_as_uint(x);
  return (u & 0x80000000u) ? ~u : (u | 0x80000000u);
}
__device__ __forceinline__ float fdec(unsigned v) {
  unsigned u = (v & 0x80000000u) ? (v & 0x7FFFFFFFu) : ~v;
  return __uint_as_float(u);
}

// lee[f,h] = sum_o le[f,o]*e[o,h]  for both layers (t<64: layer1, t>=64: layer3)
__global__ void lee_kernel(const float* __restrict__ le1, const float* __restrict__ e1,
                           const float* __restrict__ le3, const float* __restrict__ e3,
                           float* __restrict__ lee) {
  int t = threadIdx.x;
  const float* le = (t < 64) ? le1 : le3;
  const float* ee = (t < 64) ? e1 : e3;
  int u = t & 63, f = u >> 2, h = u & 3;
  float acc = 0.f;
  for (int o = 0; o < 128; ++o) acc += le[f * 128 + o] * ee[o * 4 + h];
  lee[t] = acc;
}

// xw[r,n,:] = xin[n,:] @ w[r,:,:]   grid (ceil(N/64), 4), block 256
__global__ __launch_bounds__(256) void proj_kernel(const float* __restrict__ xin,
                                                   const float* __restrict__ w,
                                                   float* __restrict__ xw, int N) {
  __shared__ float sx[PROJ_NODES * 132];  // +4 pad breaks bank aliasing
  int r = blockIdx.y;
  int nb = blockIdx.x * PROJ_NODES;
  int t = threadIdx.x;
  int nvalid = N - nb; if (nvalid > PROJ_NODES) nvalid = PROJ_NODES;
  const float4* xin4 = (const float4*)(xin + (size_t)nb * 128);
  int tot4 = nvalid * 32;
  for (int i = t; i < tot4; i += 256) {
    ((float4*)sx)[(i >> 5) * 33 + (i & 31)] = xin4[i];
  }
  __syncthreads();
  int o_idx = t & 15, n_idx = t >> 4;
  int o0 = o_idx * 8;
  const float* wg = w + (size_t)r * (128 * 128);
  float acc[4][8];
#pragma unroll
  for (int j = 0; j < 4; ++j)
#pragma unroll
    for (int i = 0; i < 8; ++i) acc[j][i] = 0.f;
#pragma unroll 4
  for (int f = 0; f < 128; ++f) {
    float4 w0 = *(const float4*)(wg + f * 128 + o0);
    float4 w1 = *(const float4*)(wg + f * 128 + o0 + 4);
#pragma unroll
    for (int j = 0; j < 4; ++j) {
      float xv = sx[(n_idx * 4 + j) * 132 + f];
      acc[j][0] += xv * w0.x; acc[j][1] += xv * w0.y;
      acc[j][2] += xv * w0.z; acc[j][3] += xv * w0.w;
      acc[j][4] += xv * w1.x; acc[j][5] += xv * w1.y;
      acc[j][6] += xv * w1.z; acc[j][7] += xv * w1.w;
    }
  }
#pragma unroll
  for (int j = 0; j < 4; ++j) {
    int n = nb + n_idx * 4 + j;
    if (n < N) {
      float* dstp = xw + ((size_t)r * N + n) * 128 + o0;
      *(float4*)dstp = make_float4(acc[j][0], acc[j][1], acc[j][2], acc[j][3]);
      *(float4*)(dstp + 4) = make_float4(acc[j][4], acc[j][5], acc[j][6], acc[j][7]);
    }
  }
}

// qn[row,h], kn[row,h] for row in [0, R*N): 64 rows/block, 4 threads/row
__global__ __launch_bounds__(256) void qk_kernel(const float* __restrict__ xw,
                                                 const float* __restrict__ q,
                                                 const float* __restrict__ k,
                                                 float* __restrict__ qn,
                                                 float* __restrict__ kn, int total) {
  __shared__ float sx[64 * 132];
  __shared__ float sq[512];
  __shared__ float sk[512];
  int rb = blockIdx.x * 64;
  int t = threadIdx.x;
  if (t < 128) ((float4*)sq)[t] = ((const float4*)q)[t];
  else if (t < 256) ((float4*)sk)[t - 128] = ((const float4*)k)[t - 128];
  int nrow = total - rb; if (nrow > 64) nrow = 64;
  const float4* s4 = (const float4*)(xw + (size_t)rb * 128);
  for (int i = t; i < nrow * 32; i += 256) {
    ((float4*)sx)[(i >> 5) * 33 + (i & 31)] = s4[i];
  }
  __syncthreads();
  int rl = t >> 2, l = t & 3;
  float aq[4] = {0, 0, 0, 0}, ak[4] = {0, 0, 0, 0};
  for (int i = 0; i < 32; ++i) {
    int o = l + 4 * i;
    float xv = sx[rl * 132 + o];
#pragma unroll
    for (int h = 0; h < 4; ++h) {
      aq[h] += xv * sq[o * 4 + h];
      ak[h] += xv * sk[o * 4 + h];
    }
  }
#pragma unroll
  for (int h = 0; h < 4; ++h) {
    aq[h] += __shfl_xor(aq[h], 1); aq[h] += __shfl_xor(aq[h], 2);
    ak[h] += __shfl_xor(ak[h], 1); ak[h] += __shfl_xor(ak[h], 2);
  }
  int row = rb + rl;
  if (l == 0 && row < total) {
    *(float4*)(qn + (size_t)row * 4) = make_float4(aq[0], aq[1], aq[2], aq[3]);
    *(float4*)(kn + (size_t)row * 4) = make_float4(ak[0], ak[1], ak[2], ak[3]);
  }
}

// ek[e,h] = sum_{f<16} ea[e,f]*lee[f,h]
__global__ __launch_bounds__(256) void ek_kernel(const float* __restrict__ ea,
                                                 const float* __restrict__ lee,
                                                 float* __restrict__ ek, int E) {
  __shared__ float sl[64];
  if (threadIdx.x < 64) sl[threadIdx.x] = lee[threadIdx.x];
  __syncthreads();
  int e = blockIdx.x * 256 + threadIdx.x;
  if (e >= E) return;
  const float4* a4 = (const float4*)(ea + (size_t)e * 16);
  float acc[4] = {0, 0, 0, 0};
#pragma unroll
  for (int i = 0; i < 4; ++i) {
    float4 v = a4[i];
    int f = i * 4;
#pragma unroll
    for (int h = 0; h < 4; ++h) {
      acc[h] += v.x * sl[f * 4 + h] + v.y * sl[(f + 1) * 4 + h] +
                v.z * sl[(f + 2) * 4 + h] + v.w * sl[(f + 3) * 4 + h];
    }
  }
  *(float4*)(ek + (size_t)e * 4) = make_float4(acc[0], acc[1], acc[2], acc[3]);
}

__global__ __launch_bounds__(256) void alpha_kernel(
    const int* __restrict__ src, const int* __restrict__ dst, const int* __restrict__ etype,
    const float* __restrict__ qn, const float* __restrict__ kn, const float* __restrict__ ek,
    float* __restrict__ alpha, unsigned* __restrict__ amax, int E, int N) {
  int e = blockIdx.x * 256 + threadIdx.x;
  if (e >= E) return;
  int s = src[e], d = dst[e], et = etype[e];
  float4 qv = *(const float4*)(qn + ((size_t)et * N + d) * 4);
  float4 kv = *(const float4*)(kn + ((size_t)et * N + s) * 4);
  float4 ev = *(const float4*)(ek + (size_t)e * 4);
  float a[4] = {qv.x + kv.x + ev.x, qv.y + kv.y + ev.y,
                qv.z + kv.z + ev.z, qv.w + kv.w + ev.w};
#pragma unroll
  for (int h = 0; h < 4; ++h) a[h] = (a[h] > 0.f) ? a[h] : NEG_SLOPE * a[h];
  *(float4*)(alpha + (size_t)e * 4) = make_float4(a[0], a[1], a[2], a[3]);
#pragma unroll
  for (int h = 0; h < 4; ++h) atomicMax(&amax[(size_t)d * 4 + h], fenc(a[h]));
}

__global__ __launch_bounds__(256) void exp_kernel(const int* __restrict__ dst,
                                                  float* __restrict__ alpha,
                                                  const unsigned* __restrict__ amax,
                                                  float* __restrict__ den, int E) {
  int e = blockIdx.x * 256 + threadIdx.x;
  if (e >= E) return;
  int d = dst[e];
  float4 av = *(const float4*)(alpha + (size_t)e * 4);
  uint4 mv = *(const uint4*)(amax + (size_t)d * 4);
  float e0 = __expf(av.x - fdec(mv.x));
  float e1 = __expf(av.y - fdec(mv.y));
  float e2 = __expf(av.z - fdec(mv.z));
  float e3 = __expf(av.w - fdec(mv.w));
  *(float4*)(alpha + (size_t)e * 4) = make_float4(e0, e1, e2, e3);
  atomicAdd(&den[(size_t)d * 4 + 0], e0);
  atomicAdd(&den[(size_t)d * 4 + 1], e1);
  atomicAdd(&den[(size_t)d * 4 + 2], e2);
  atomicAdd(&den[(size_t)d * 4 + 3], e3);
}

// 32 lanes per edge, each lane handles 4 channels (one float4 of the 128-wide row)
__global__ __launch_bounds__(256) void agg_kernel(
    const int* __restrict__ src, const int* __restrict__ dst, const int* __restrict__ etype,
    const float* __restrict__ ex, const float* __restrict__ den,
    const float* __restrict__ xw, float* __restrict__ agg, int E, int N) {
  int tid = blockIdx.x * 256 + threadIdx.x;
  int e = tid >> 5;
  if (e >= E) return;
  int c = tid & 31;  // float4 index within 128-wide row
  int h = c >> 3;
  int s = src[e], d = dst[e], et = etype[e];
  float w = ex[(size_t)e * 4 + h] / (den[(size_t)d * 4 + h] + SOFT_EPS);
  float4 xv = *(const float4*)(xw + ((size_t)et * N + s) * 128 + c * 4);
  float* o = agg + (size_t)d * 128 + c * 4;
  atomicAdd(o + 0, w * xv.x);
  atomicAdd(o + 1, w * xv.y);
  atomicAdd(o + 2, w * xv.z);
  atomicAdd(o + 3, w * xv.w);
}

__global__ __launch_bounds__(256) void epi1_kernel(const float* __restrict__ agg,
                                                   const float* __restrict__ b,
                                                   float* __restrict__ h, int N) {
  int i = blockIdx.x * 256 + threadIdx.x;  // float4 index over N*32
  if (i >= N * 32) return;
  float4 v = ((const float4*)agg)[i];
  float4 bv = ((const float4*)b)[i & 31];
  v.x += bv.x; v.y += bv.y; v.z += bv.z; v.w += bv.w;
  v.x = v.x > 0.f ? v.x : 0.f;
  v.y = v.y > 0.f ? v.y : 0.f;
  v.z = v.z > 0.f ? v.z : 0.f;
  v.w = v.w > 0.f ? v.w : 0.f;
  ((float4*)h)[i] = v;
}

__global__ __launch_bounds__(256) void epi2_kernel(const float* __restrict__ agg,
                                                   const float* __restrict__ b3,
                                                   float* __restrict__ out, int N) {
  int i = blockIdx.x * 256 + threadIdx.x;  // scalar index over N*32
  if (i >= N * 32) return;
  int n = i >> 5, c = i & 31;
  const float* row = agg + (size_t)n * 128;
  out[i] = 0.25f * (row[c] + row[32 + c] + row[64 + c] + row[96 + c]) + b3[c];
}

extern "C" void kernel_launch(void* const* d_in, const int* in_sizes, int n_in,
                              void* d_out, int out_size, void* d_ws, size_t ws_size,
                              hipStream_t stream) {
  const float* x   = (const float*)d_in[0];
  const int*   ei  = (const int*)d_in[1];
  const float* ea  = (const float*)d_in[2];
  const int*   etp = (const int*)d_in[3];
  const float* w1  = (const float*)d_in[4];
  const float* q1  = (const float*)d_in[5];
  const float* k1  = (const float*)d_in[6];
  const float* e1  = (const float*)d_in[7];
  const float* le1 = (const float*)d_in[8];
  const float* b1  = (const float*)d_in[9];
  const float* w3  = (const float*)d_in[10];
  const float* q3  = (const float*)d_in[11];
  const float* k3  = (const float*)d_in[12];
  const float* e3  = (const float*)d_in[13];
  const float* le3 = (const float*)d_in[14];
  const float* b3  = (const float*)d_in[15];
  const int N = in_sizes[0] / 128;
  const int E = in_sizes[3];
  const int* srcp = ei;
  const int* dstp = ei + E;

  // workspace layout (fp32 elems): xw[4*N*128] qn[4N*4] kn[4N*4] ek[E*4] alpha[E*4]
  //                                amax[N*4 u32] den[N*4] agg[N*128] hbuf[N*128] lee[128]
  float* ws   = (float*)d_ws;
  float* xw   = ws;
  float* qn   = xw + (size_t)4 * N * 128;
  float* kn   = qn + (size_t)4 * N * 4;
  float* ekb  = kn + (size_t)4 * N * 4;
  float* alph = ekb + (size_t)E * 4;
  unsigned* amax = (unsigned*)(alph + (size_t)E * 4);
  float* den  = (float*)(amax + (size_t)N * 4);
  float* agg  = den + (size_t)N * 4;
  float* hbuf = agg + (size_t)N * 128;
  float* leeb = hbuf + (size_t)N * 128;
  (void)ws_size; (void)n_in; (void)out_size;

  int pgx  = (N + PROJ_NODES - 1) / PROJ_NODES;
  int qkb  = (4 * N + 63) / 64;
  int eb   = (E + 255) / 256;
  int ab   = (int)(((size_t)E * 32 + 255) / 256);
  int nb32 = (N * 32 + 255) / 256;

  lee_kernel<<<1, 128, 0, stream>>>(le1, e1, le3, e3, leeb);

  for (int layer = 0; layer < 2; ++layer) {
    const float* xin = layer ? hbuf : x;
    const float* w   = layer ? w3 : w1;
    const float* q   = layer ? q3 : q1;
    const float* k   = layer ? k3 : k1;
    const float* leep = leeb + (layer ? 64 : 0);

    proj_kernel<<<dim3(pgx, 4), 256, 0, stream>>>(xin, w, xw, N);
    qk_kernel<<<qkb, 256, 0, stream>>>(xw, q, k, qn, kn, 4 * N);
    ek_kernel<<<eb, 256, 0, stream>>>(ea, leep, ekb, E);

    hipMemsetAsync(amax, 0, (size_t)N * 4 * sizeof(unsigned), stream);
    hipMemsetAsync(den, 0, (size_t)N * 4 * sizeof(float), stream);
    hipMemsetAsync(agg, 0, (size_t)N * 128 * sizeof(float), stream);

    alpha_kernel<<<eb, 256, 0, stream>>>(srcp, dstp, etp, qn, kn, ekb, alph, amax, E, N);
    exp_kernel<<<eb, 256, 0, stream>>>(dstp, alph, amax, den, E);
    agg_kernel<<<ab, 256, 0, stream>>>(srcp, dstp, etp, alph, den, xw, agg, E, N);

    if (layer == 0)
      epi1_kernel<<<nb32, 256, 0, stream>>>(agg, b1, hbuf, N);
    else
      epi2_kernel<<<nb32, 256, 0, stream>>>(agg, b3, (float*)d_out, N);
  }
}

// Round 2
// 910.751 us; speedup vs baseline: 4.1156x; 4.1156x over previous
//
#include <hip/hip_runtime.h>

// RGATNetwork: 2x RGATConv (R=4, H=4, C=32, HC=128, F_E=16) on N=50k nodes, E=800k edges.
// R2: dst-sorted CSR built once per call; aggregation is gather-based (one wave
// per destination node) with fused softmax (max, sum-exp, normalize), bias, and
// relu/head-mean epilogue. No fp32 atomics anywhere in the hot path.

#define NEG_SLOPE 0.2f
#define SOFT_EPS 1e-16f
#define PROJ_NODES 64

// lee[f,h] = sum_o le[f,o]*e[o,h]  for both layers (t<64: layer1, t>=64: layer3)
__global__ void lee_kernel(const float* __restrict__ le1, const float* __restrict__ e1,
                           const float* __restrict__ le3, const float* __restrict__ e3,
                           float* __restrict__ lee) {
  int t = threadIdx.x;
  const float* le = (t < 64) ? le1 : le3;
  const float* ee = (t < 64) ? e1 : e3;
  int u = t & 63, f = u >> 2, h = u & 3;
  float acc = 0.f;
  for (int o = 0; o < 128; ++o) acc += le[f * 128 + o] * ee[o * 4 + h];
  lee[t] = acc;
}

// ---- CSR build (once per call) ----
__global__ __launch_bounds__(256) void hist_kernel(const int* __restrict__ dst,
                                                   int* __restrict__ deg, int E) {
  int e = blockIdx.x * 256 + threadIdx.x;
  if (e < E) atomicAdd(&deg[dst[e]], 1);
}

// single-block exclusive scan of deg[0..N) -> row_start[0..N], cursor copy
__global__ __launch_bounds__(256) void scan_kernel(const int* __restrict__ deg,
                                                   int* __restrict__ row_start,
                                                   int* __restrict__ cursor, int N) {
  __shared__ int part[256];
  __shared__ int off[257];
  int t = threadIdx.x;
  int chunk = (N + 255) / 256;
  int b = t * chunk;
  int e = b + chunk; if (e > N) e = N;
  int s = 0;
  for (int i = b; i < e; ++i) s += deg[i];
  part[t] = s;
  __syncthreads();
  if (t == 0) {
    int acc = 0;
    for (int i = 0; i < 256; ++i) { off[i] = acc; acc += part[i]; }
    off[256] = acc;
  }
  __syncthreads();
  int acc = off[t];
  for (int i = b; i < e; ++i) {
    row_start[i] = acc; cursor[i] = acc;
    acc += deg[i];
  }
  if (t == 255) row_start[N] = off[256];
}

__global__ __launch_bounds__(256) void scatter_kernel(
    const int* __restrict__ src, const int* __restrict__ dst, const int* __restrict__ et,
    int* __restrict__ cursor, int* __restrict__ es_src, int* __restrict__ es_dst,
    int* __restrict__ es_et, int* __restrict__ es_eid, int E) {
  int e = blockIdx.x * 256 + threadIdx.x;
  if (e >= E) return;
  int d = dst[e];
  int pos = atomicAdd(&cursor[d], 1);
  es_src[pos] = src[e];
  es_dst[pos] = d;
  es_et[pos] = et[e];
  es_eid[pos] = e;
}

// ---- per-layer kernels ----

// xw[r,n,:] = xin[n,:] @ w[r,:,:]   grid (ceil(N/64), 4), block 256
__global__ __launch_bounds__(256) void proj_kernel(const float* __restrict__ xin,
                                                   const float* __restrict__ w,
                                                   float* __restrict__ xw, int N) {
  __shared__ float sx[PROJ_NODES * 132];
  int r = blockIdx.y;
  int nb = blockIdx.x * PROJ_NODES;
  int t = threadIdx.x;
  int nvalid = N - nb; if (nvalid > PROJ_NODES) nvalid = PROJ_NODES;
  const float4* xin4 = (const float4*)(xin + (size_t)nb * 128);
  int tot4 = nvalid * 32;
  for (int i = t; i < tot4; i += 256) {
    ((float4*)sx)[(i >> 5) * 33 + (i & 31)] = xin4[i];
  }
  __syncthreads();
  int o_idx = t & 15, n_idx = t >> 4;
  int o0 = o_idx * 8;
  const float* wg = w + (size_t)r * (128 * 128);
  float acc[4][8];
#pragma unroll
  for (int j = 0; j < 4; ++j)
#pragma unroll
    for (int i = 0; i < 8; ++i) acc[j][i] = 0.f;
#pragma unroll 4
  for (int f = 0; f < 128; ++f) {
    float4 w0 = *(const float4*)(wg + f * 128 + o0);
    float4 w1 = *(const float4*)(wg + f * 128 + o0 + 4);
#pragma unroll
    for (int j = 0; j < 4; ++j) {
      float xv = sx[(n_idx * 4 + j) * 132 + f];
      acc[j][0] += xv * w0.x; acc[j][1] += xv * w0.y;
      acc[j][2] += xv * w0.z; acc[j][3] += xv * w0.w;
      acc[j][4] += xv * w1.x; acc[j][5] += xv * w1.y;
      acc[j][6] += xv * w1.z; acc[j][7] += xv * w1.w;
    }
  }
#pragma unroll
  for (int j = 0; j < 4; ++j) {
    int n = nb + n_idx * 4 + j;
    if (n < N) {
      float* dstp = xw + ((size_t)r * N + n) * 128 + o0;
      *(float4*)dstp = make_float4(acc[j][0], acc[j][1], acc[j][2], acc[j][3]);
      *(float4*)(dstp + 4) = make_float4(acc[j][4], acc[j][5], acc[j][6], acc[j][7]);
    }
  }
}

// qn[row,h], kn[row,h] for row in [0, R*N): 64 rows/block, 4 threads/row
__global__ __launch_bounds__(256) void qk_kernel(const float* __restrict__ xw,
                                                 const float* __restrict__ q,
                                                 const float* __restrict__ k,
                                                 float* __restrict__ qn,
                                                 float* __restrict__ kn, int total) {
  __shared__ float sx[64 * 132];
  __shared__ float sq[512];
  __shared__ float sk[512];
  int rb = blockIdx.x * 64;
  int t = threadIdx.x;
  if (t < 128) ((float4*)sq)[t] = ((const float4*)q)[t];
  else if (t < 256) ((float4*)sk)[t - 128] = ((const float4*)k)[t - 128];
  int nrow = total - rb; if (nrow > 64) nrow = 64;
  const float4* s4 = (const float4*)(xw + (size_t)rb * 128);
  for (int i = t; i < nrow * 32; i += 256) {
    ((float4*)sx)[(i >> 5) * 33 + (i & 31)] = s4[i];
  }
  __syncthreads();
  int rl = t >> 2, l = t & 3;
  float aq[4] = {0, 0, 0, 0}, ak[4] = {0, 0, 0, 0};
  for (int i = 0; i < 32; ++i) {
    int o = l + 4 * i;
    float xv = sx[rl * 132 + o];
#pragma unroll
    for (int h = 0; h < 4; ++h) {
      aq[h] += xv * sq[o * 4 + h];
      ak[h] += xv * sk[o * 4 + h];
    }
  }
#pragma unroll
  for (int h = 0; h < 4; ++h) {
    aq[h] += __shfl_xor(aq[h], 1); aq[h] += __shfl_xor(aq[h], 2);
    ak[h] += __shfl_xor(ak[h], 1); ak[h] += __shfl_xor(ak[h], 2);
  }
  int row = rb + rl;
  if (l == 0 && row < total) {
    *(float4*)(qn + (size_t)row * 4) = make_float4(aq[0], aq[1], aq[2], aq[3]);
    *(float4*)(kn + (size_t)row * 4) = make_float4(ak[0], ak[1], ak[2], ak[3]);
  }
}

// ek[e,h] = sum_{f<16} ea[e,f]*lee[f,h]
__global__ __launch_bounds__(256) void ek_kernel(const float* __restrict__ ea,
                                                 const float* __restrict__ lee,
                                                 float* __restrict__ ek, int E) {
  __shared__ float sl[64];
  if (threadIdx.x < 64) sl[threadIdx.x] = lee[threadIdx.x];
  __syncthreads();
  int e = blockIdx.x * 256 + threadIdx.x;
  if (e >= E) return;
  const float4* a4 = (const float4*)(ea + (size_t)e * 16);
  float acc[4] = {0, 0, 0, 0};
#pragma unroll
  for (int i = 0; i < 4; ++i) {
    float4 v = a4[i];
    int f = i * 4;
#pragma unroll
    for (int h = 0; h < 4; ++h) {
      acc[h] += v.x * sl[f * 4 + h] + v.y * sl[(f + 1) * 4 + h] +
                v.z * sl[(f + 2) * 4 + h] + v.w * sl[(f + 3) * 4 + h];
    }
  }
  *(float4*)(ek + (size_t)e * 4) = make_float4(acc[0], acc[1], acc[2], acc[3]);
}

// alpha in dst-sorted order: alpha_s[i,h] = lrelu(qn[et,d]+kn[et,s]+ek[e])
__global__ __launch_bounds__(256) void alpha_kernel(
    const int* __restrict__ es_src, const int* __restrict__ es_dst,
    const int* __restrict__ es_et, const int* __restrict__ es_eid,
    const float* __restrict__ qn, const float* __restrict__ kn,
    const float* __restrict__ ek, float* __restrict__ alpha_s, int E, int N) {
  int i = blockIdx.x * 256 + threadIdx.x;
  if (i >= E) return;
  int s = es_src[i], d = es_dst[i], et = es_et[i], e = es_eid[i];
  float4 qv = *(const float4*)(qn + ((size_t)et * N + d) * 4);
  float4 kv = *(const float4*)(kn + ((size_t)et * N + s) * 4);
  float4 ev = *(const float4*)(ek + (size_t)e * 4);
  float a0 = qv.x + kv.x + ev.x, a1 = qv.y + kv.y + ev.y;
  float a2 = qv.z + kv.z + ev.z, a3 = qv.w + kv.w + ev.w;
  a0 = a0 > 0.f ? a0 : NEG_SLOPE * a0;
  a1 = a1 > 0.f ? a1 : NEG_SLOPE * a1;
  a2 = a2 > 0.f ? a2 : NEG_SLOPE * a2;
  a3 = a3 > 0.f ? a3 : NEG_SLOPE * a3;
  *(float4*)(alpha_s + (size_t)i * 4) = make_float4(a0, a1, a2, a3);
}

// fused softmax + gather-aggregate + epilogue. One wave (64 lanes) per dst node.
// lane l owns channels [2l, 2l+1] of the 128-wide output row; head h = l>>4.
__global__ __launch_bounds__(256) void agg_kernel(
    const int* __restrict__ es_src, const int* __restrict__ es_et,
    const int* __restrict__ row_start, const float* __restrict__ alpha_s,
    const float* __restrict__ xw, const float* __restrict__ bias,
    float* __restrict__ out, int N, int concat) {
  int d = blockIdx.x * 4 + (threadIdx.x >> 6);
  if (d >= N) return;
  int lane = threadIdx.x & 63;
  int rs = row_start[d], re = row_start[d + 1];

  // segment max over 4 heads
  float4 mx = make_float4(-1e30f, -1e30f, -1e30f, -1e30f);
  for (int i = rs + lane; i < re; i += 64) {
    float4 a = ((const float4*)alpha_s)[i];
    mx.x = fmaxf(mx.x, a.x); mx.y = fmaxf(mx.y, a.y);
    mx.z = fmaxf(mx.z, a.z); mx.w = fmaxf(mx.w, a.w);
  }
#pragma unroll
  for (int o = 32; o >= 1; o >>= 1) {
    mx.x = fmaxf(mx.x, __shfl_xor(mx.x, o));
    mx.y = fmaxf(mx.y, __shfl_xor(mx.y, o));
    mx.z = fmaxf(mx.z, __shfl_xor(mx.z, o));
    mx.w = fmaxf(mx.w, __shfl_xor(mx.w, o));
  }
  // segment sum-exp
  float4 sm = make_float4(0.f, 0.f, 0.f, 0.f);
  for (int i = rs + lane; i < re; i += 64) {
    float4 a = ((const float4*)alpha_s)[i];
    sm.x += __expf(a.x - mx.x); sm.y += __expf(a.y - mx.y);
    sm.z += __expf(a.z - mx.z); sm.w += __expf(a.w - mx.w);
  }
#pragma unroll
  for (int o = 32; o >= 1; o >>= 1) {
    sm.x += __shfl_xor(sm.x, o); sm.y += __shfl_xor(sm.y, o);
    sm.z += __shfl_xor(sm.z, o); sm.w += __shfl_xor(sm.w, o);
  }
  int h = lane >> 4;
  float mxh = (h == 0) ? mx.x : (h == 1) ? mx.y : (h == 2) ? mx.z : mx.w;
  float smh = (h == 0) ? sm.x : (h == 1) ? sm.y : (h == 2) ? sm.z : sm.w;
  float rden = 1.f / (smh + SOFT_EPS);

  // gather-accumulate: all 64 lanes cooperate per edge (512 B coalesced row read)
  float ax = 0.f, ay = 0.f;
  for (int i = rs; i < re; ++i) {
    int s = es_src[i], et = es_et[i];
    float w = __expf(alpha_s[(size_t)i * 4 + h] - mxh) * rden;
    float2 xv = *(const float2*)(xw + ((size_t)et * N + s) * 128 + lane * 2);
    ax += w * xv.x; ay += w * xv.y;
  }

  if (concat) {  // layer 1: relu(agg + b1) -> hbuf[d,128]
    float2 bv = *(const float2*)(bias + lane * 2);
    float vx = ax + bv.x, vy = ay + bv.y;
    vx = vx > 0.f ? vx : 0.f;
    vy = vy > 0.f ? vy : 0.f;
    *(float2*)(out + (size_t)d * 128 + lane * 2) = make_float2(vx, vy);
  } else {       // layer 2: mean over heads + b3 -> out[d,32]
#pragma unroll
    for (int o = 16; o <= 32; o <<= 1) {
      ax += __shfl_xor(ax, o);
      ay += __shfl_xor(ay, o);
    }
    if (lane < 16) {
      float2 bv = *(const float2*)(bias + lane * 2);
      *(float2*)(out + (size_t)d * 32 + lane * 2) =
          make_float2(0.25f * ax + bv.x, 0.25f * ay + bv.y);
    }
  }
}

extern "C" void kernel_launch(void* const* d_in, const int* in_sizes, int n_in,
                              void* d_out, int out_size, void* d_ws, size_t ws_size,
                              hipStream_t stream) {
  const float* x   = (const float*)d_in[0];
  const int*   ei  = (const int*)d_in[1];
  const float* ea  = (const float*)d_in[2];
  const int*   etp = (const int*)d_in[3];
  const float* w1  = (const float*)d_in[4];
  const float* q1  = (const float*)d_in[5];
  const float* k1  = (const float*)d_in[6];
  const float* e1  = (const float*)d_in[7];
  const float* le1 = (const float*)d_in[8];
  const float* b1  = (const float*)d_in[9];
  const float* w3  = (const float*)d_in[10];
  const float* q3  = (const float*)d_in[11];
  const float* k3  = (const float*)d_in[12];
  const float* e3  = (const float*)d_in[13];
  const float* le3 = (const float*)d_in[14];
  const float* b3  = (const float*)d_in[15];
  const int N = in_sizes[0] / 128;
  const int E = in_sizes[3];
  const int* srcp = ei;
  const int* dstp = ei + E;

  // workspace layout
  float* ws   = (float*)d_ws;
  float* xw   = ws;                                  // 4*N*128
  float* qn   = xw + (size_t)4 * N * 128;            // 4*N*4
  float* kn   = qn + (size_t)4 * N * 4;              // 4*N*4
  float* ekb  = kn + (size_t)4 * N * 4;              // E*4
  float* alph = ekb + (size_t)E * 4;                 // E*4
  float* hbuf = alph + (size_t)E * 4;                // N*128
  float* leeb = hbuf + (size_t)N * 128;              // 128
  int* deg      = (int*)(leeb + 128);                // N
  int* rowst    = deg + N;                           // N+1
  int* cursor   = rowst + N + 1;                     // N
  int* es_src   = cursor + N;                        // E
  int* es_dst   = es_src + E;                        // E
  int* es_et    = es_dst + E;                        // E
  int* es_eid   = es_et + E;                         // E
  (void)ws_size; (void)n_in; (void)out_size;

  int pgx  = (N + PROJ_NODES - 1) / PROJ_NODES;
  int qkb  = (4 * N + 63) / 64;
  int eb   = (E + 255) / 256;
  int nb4  = (N + 3) / 4;

  // CSR build (graph identical for both layers)
  hipMemsetAsync(deg, 0, (size_t)N * sizeof(int), stream);
  hist_kernel<<<eb, 256, 0, stream>>>(dstp, deg, E);
  scan_kernel<<<1, 256, 0, stream>>>(deg, rowst, cursor, N);
  scatter_kernel<<<eb, 256, 0, stream>>>(srcp, dstp, etp, cursor,
                                         es_src, es_dst, es_et, es_eid, E);
  lee_kernel<<<1, 128, 0, stream>>>(le1, e1, le3, e3, leeb);

  for (int layer = 0; layer < 2; ++layer) {
    const float* xin = layer ? hbuf : x;
    const float* w   = layer ? w3 : w1;
    const float* q   = layer ? q3 : q1;
    const float* k   = layer ? k3 : k1;
    const float* leep = leeb + (layer ? 64 : 0);
    const float* bias = layer ? b3 : b1;
    float* outp = layer ? (float*)d_out : hbuf;

    proj_kernel<<<dim3(pgx, 4), 256, 0, stream>>>(xin, w, xw, N);
    qk_kernel<<<qkb, 256, 0, stream>>>(xw, q, k, qn, kn, 4 * N);
    ek_kernel<<<eb, 256, 0, stream>>>(ea, leep, ekb, E);
    alpha_kernel<<<eb, 256, 0, stream>>>(es_src, es_dst, es_et, es_eid,
                                         qn, kn, ekb, alph, E, N);
    agg_kernel<<<nb4, 256, 0, stream>>>(es_src, es_et, rowst, alph, xw,
                                        bias, outp, N, layer == 0 ? 1 : 0);
  }
}

// Round 3
// 858.994 us; speedup vs baseline: 4.3635x; 1.0603x over previous
//
#include <hip/hip_runtime.h>

// RGATNetwork: 2x RGATConv (R=4, H=4, C=32, HC=128, F_E=16) on N=50k nodes, E=800k edges.
// R3: proj_kernel rewritten as LDS-staged register-blocked GEMM:
//     128-node x 128-out tile per block (one relation), BK=32 chunks,
//     8x8 thread tile, all inner LDS reads ds_read_b128. ~105 TF LDS-bound ceiling
//     vs 48 TF for the old L2-thrashing version.
// Rest of pipeline unchanged from R2 (CSR gather aggregation, fused softmax).

#define NEG_SLOPE 0.2f
#define SOFT_EPS 1e-16f

// lee[f,h] = sum_o le[f,o]*e[o,h]  for both layers (t<64: layer1, t>=64: layer3)
__global__ void lee_kernel(const float* __restrict__ le1, const float* __restrict__ e1,
                           const float* __restrict__ le3, const float* __restrict__ e3,
                           float* __restrict__ lee) {
  int t = threadIdx.x;
  const float* le = (t < 64) ? le1 : le3;
  const float* ee = (t < 64) ? e1 : e3;
  int u = t & 63, f = u >> 2, h = u & 3;
  float acc = 0.f;
  for (int o = 0; o < 128; ++o) acc += le[f * 128 + o] * ee[o * 4 + h];
  lee[t] = acc;
}

// ---- CSR build (once per call) ----
__global__ __launch_bounds__(256) void hist_kernel(const int* __restrict__ dst,
                                                   int* __restrict__ deg, int E) {
  int e = blockIdx.x * 256 + threadIdx.x;
  if (e < E) atomicAdd(&deg[dst[e]], 1);
}

__global__ __launch_bounds__(256) void scan_kernel(const int* __restrict__ deg,
                                                   int* __restrict__ row_start,
                                                   int* __restrict__ cursor, int N) {
  __shared__ int part[256];
  __shared__ int off[257];
  int t = threadIdx.x;
  int chunk = (N + 255) / 256;
  int b = t * chunk;
  int e = b + chunk; if (e > N) e = N;
  int s = 0;
  for (int i = b; i < e; ++i) s += deg[i];
  part[t] = s;
  __syncthreads();
  if (t == 0) {
    int acc = 0;
    for (int i = 0; i < 256; ++i) { off[i] = acc; acc += part[i]; }
    off[256] = acc;
  }
  __syncthreads();
  int acc = off[t];
  for (int i = b; i < e; ++i) {
    row_start[i] = acc; cursor[i] = acc;
    acc += deg[i];
  }
  if (t == 255) row_start[N] = off[256];
}

__global__ __launch_bounds__(256) void scatter_kernel(
    const int* __restrict__ src, const int* __restrict__ dst, const int* __restrict__ et,
    int* __restrict__ cursor, int* __restrict__ es_src, int* __restrict__ es_dst,
    int* __restrict__ es_et, int* __restrict__ es_eid, int E) {
  int e = blockIdx.x * 256 + threadIdx.x;
  if (e >= E) return;
  int d = dst[e];
  int pos = atomicAdd(&cursor[d], 1);
  es_src[pos] = src[e];
  es_dst[pos] = d;
  es_et[pos] = et[e];
  es_eid[pos] = e;
}

// ---- proj: xw[r,n,:] = xin[n,:] @ w[r,:,:] ----
// grid (ceil(N/128), R), block 256. 128x128 tile, BK=32, 8x8 per thread.
#define SX_STRIDE 36  // 32 + 4 pad (multiple of 4 for b128 alignment; tn-step hits banks 0,4,8,12)
__global__ __launch_bounds__(256) void proj_kernel(const float* __restrict__ xin,
                                                   const float* __restrict__ w,
                                                   float* __restrict__ xw, int N) {
  __shared__ float sx[128 * SX_STRIDE];  // [node][f]  18 KB
  __shared__ float sw[32 * 128];         // [f][o]     16 KB
  int r = blockIdx.y;
  int nb = blockIdx.x * 128;
  int t = threadIdx.x;
  int tn = t >> 4;   // node group 0..15: nodes tn + 16*j
  int to = t & 15;   // out group 0..15: outs to*4..+3 and 64+to*4..+3
  const float* wg = w + (size_t)r * (128 * 128);

  float acc[8][8];
#pragma unroll
  for (int j = 0; j < 8; ++j)
#pragma unroll
    for (int i = 0; i < 8; ++i) acc[j][i] = 0.f;

  for (int kc = 0; kc < 4; ++kc) {
    int k0 = kc * 32;
    // stage x chunk: 128 nodes x 32 f  (1024 float4, 4 per thread)
#pragma unroll
    for (int it = 0; it < 4; ++it) {
      int i = it * 256 + t;
      int n = i >> 3, f4 = i & 7;
      int ng = nb + n;
      float4 v = make_float4(0.f, 0.f, 0.f, 0.f);
      if (ng < N) v = *(const float4*)(xin + (size_t)ng * 128 + k0 + f4 * 4);
      *(float4*)(sx + n * SX_STRIDE + f4 * 4) = v;
    }
    // stage w chunk: 32 f x 128 o (1024 float4, 4 per thread)
#pragma unroll
    for (int it = 0; it < 4; ++it) {
      int i = it * 256 + t;
      int f = i >> 5, o4 = i & 31;
      *(float4*)(sw + f * 128 + o4 * 4) =
          *(const float4*)(wg + (size_t)(k0 + f) * 128 + o4 * 4);
    }
    __syncthreads();

#pragma unroll
    for (int f4 = 0; f4 < 8; ++f4) {
      float4 xf[8];
#pragma unroll
      for (int j = 0; j < 8; ++j)
        xf[j] = *(const float4*)(sx + (tn + 16 * j) * SX_STRIDE + f4 * 4);
#pragma unroll
      for (int ff = 0; ff < 4; ++ff) {
        float4 wa = *(const float4*)(sw + (f4 * 4 + ff) * 128 + to * 4);
        float4 wb = *(const float4*)(sw + (f4 * 4 + ff) * 128 + 64 + to * 4);
#pragma unroll
        for (int j = 0; j < 8; ++j) {
          float xv = (ff == 0) ? xf[j].x : (ff == 1) ? xf[j].y : (ff == 2) ? xf[j].z : xf[j].w;
          acc[j][0] += xv * wa.x; acc[j][1] += xv * wa.y;
          acc[j][2] += xv * wa.z; acc[j][3] += xv * wa.w;
          acc[j][4] += xv * wb.x; acc[j][5] += xv * wb.y;
          acc[j][6] += xv * wb.z; acc[j][7] += xv * wb.w;
        }
      }
    }
    __syncthreads();
  }

#pragma unroll
  for (int j = 0; j < 8; ++j) {
    int n = nb + tn + 16 * j;
    if (n < N) {
      float* dstp = xw + ((size_t)r * N + n) * 128;
      *(float4*)(dstp + to * 4) = make_float4(acc[j][0], acc[j][1], acc[j][2], acc[j][3]);
      *(float4*)(dstp + 64 + to * 4) = make_float4(acc[j][4], acc[j][5], acc[j][6], acc[j][7]);
    }
  }
}

// qn[row,h], kn[row,h] for row in [0, R*N): 64 rows/block, 4 threads/row
__global__ __launch_bounds__(256) void qk_kernel(const float* __restrict__ xw,
                                                 const float* __restrict__ q,
                                                 const float* __restrict__ k,
                                                 float* __restrict__ qn,
                                                 float* __restrict__ kn, int total) {
  __shared__ float sx[64 * 132];
  __shared__ float sq[512];
  __shared__ float sk[512];
  int rb = blockIdx.x * 64;
  int t = threadIdx.x;
  if (t < 128) ((float4*)sq)[t] = ((const float4*)q)[t];
  else if (t < 256) ((float4*)sk)[t - 128] = ((const float4*)k)[t - 128];
  int nrow = total - rb; if (nrow > 64) nrow = 64;
  const float4* s4 = (const float4*)(xw + (size_t)rb * 128);
  for (int i = t; i < nrow * 32; i += 256) {
    ((float4*)sx)[(i >> 5) * 33 + (i & 31)] = s4[i];
  }
  __syncthreads();
  int rl = t >> 2, l = t & 3;
  float aq[4] = {0, 0, 0, 0}, ak[4] = {0, 0, 0, 0};
  for (int i = 0; i < 32; ++i) {
    int o = l + 4 * i;
    float xv = sx[rl * 132 + o];
#pragma unroll
    for (int h = 0; h < 4; ++h) {
      aq[h] += xv * sq[o * 4 + h];
      ak[h] += xv * sk[o * 4 + h];
    }
  }
#pragma unroll
  for (int h = 0; h < 4; ++h) {
    aq[h] += __shfl_xor(aq[h], 1); aq[h] += __shfl_xor(aq[h], 2);
    ak[h] += __shfl_xor(ak[h], 1); ak[h] += __shfl_xor(ak[h], 2);
  }
  int row = rb + rl;
  if (l == 0 && row < total) {
    *(float4*)(qn + (size_t)row * 4) = make_float4(aq[0], aq[1], aq[2], aq[3]);
    *(float4*)(kn + (size_t)row * 4) = make_float4(ak[0], ak[1], ak[2], ak[3]);
  }
}

// ek[e,h] = sum_{f<16} ea[e,f]*lee[f,h]
__global__ __launch_bounds__(256) void ek_kernel(const float* __restrict__ ea,
                                                 const float* __restrict__ lee,
                                                 float* __restrict__ ek, int E) {
  __shared__ float sl[64];
  if (threadIdx.x < 64) sl[threadIdx.x] = lee[threadIdx.x];
  __syncthreads();
  int e = blockIdx.x * 256 + threadIdx.x;
  if (e >= E) return;
  const float4* a4 = (const float4*)(ea + (size_t)e * 16);
  float acc[4] = {0, 0, 0, 0};
#pragma unroll
  for (int i = 0; i < 4; ++i) {
    float4 v = a4[i];
    int f = i * 4;
#pragma unroll
    for (int h = 0; h < 4; ++h) {
      acc[h] += v.x * sl[f * 4 + h] + v.y * sl[(f + 1) * 4 + h] +
                v.z * sl[(f + 2) * 4 + h] + v.w * sl[(f + 3) * 4 + h];
    }
  }
  *(float4*)(ek + (size_t)e * 4) = make_float4(acc[0], acc[1], acc[2], acc[3]);
}

// alpha in dst-sorted order
__global__ __launch_bounds__(256) void alpha_kernel(
    const int* __restrict__ es_src, const int* __restrict__ es_dst,
    const int* __restrict__ es_et, const int* __restrict__ es_eid,
    const float* __restrict__ qn, const float* __restrict__ kn,
    const float* __restrict__ ek, float* __restrict__ alpha_s, int E, int N) {
  int i = blockIdx.x * 256 + threadIdx.x;
  if (i >= E) return;
  int s = es_src[i], d = es_dst[i], et = es_et[i], e = es_eid[i];
  float4 qv = *(const float4*)(qn + ((size_t)et * N + d) * 4);
  float4 kv = *(const float4*)(kn + ((size_t)et * N + s) * 4);
  float4 ev = *(const float4*)(ek + (size_t)e * 4);
  float a0 = qv.x + kv.x + ev.x, a1 = qv.y + kv.y + ev.y;
  float a2 = qv.z + kv.z + ev.z, a3 = qv.w + kv.w + ev.w;
  a0 = a0 > 0.f ? a0 : NEG_SLOPE * a0;
  a1 = a1 > 0.f ? a1 : NEG_SLOPE * a1;
  a2 = a2 > 0.f ? a2 : NEG_SLOPE * a2;
  a3 = a3 > 0.f ? a3 : NEG_SLOPE * a3;
  *(float4*)(alpha_s + (size_t)i * 4) = make_float4(a0, a1, a2, a3);
}

// fused softmax + gather-aggregate + epilogue. One wave (64 lanes) per dst node.
__global__ __launch_bounds__(256) void agg_kernel(
    const int* __restrict__ es_src, const int* __restrict__ es_et,
    const int* __restrict__ row_start, const float* __restrict__ alpha_s,
    const float* __restrict__ xw, const float* __restrict__ bias,
    float* __restrict__ out, int N, int concat) {
  int d = blockIdx.x * 4 + (threadIdx.x >> 6);
  if (d >= N) return;
  int lane = threadIdx.x & 63;
  int rs = row_start[d], re = row_start[d + 1];

  float4 mx = make_float4(-1e30f, -1e30f, -1e30f, -1e30f);
  for (int i = rs + lane; i < re; i += 64) {
    float4 a = ((const float4*)alpha_s)[i];
    mx.x = fmaxf(mx.x, a.x); mx.y = fmaxf(mx.y, a.y);
    mx.z = fmaxf(mx.z, a.z); mx.w = fmaxf(mx.w, a.w);
  }
#pragma unroll
  for (int o = 32; o >= 1; o >>= 1) {
    mx.x = fmaxf(mx.x, __shfl_xor(mx.x, o));
    mx.y = fmaxf(mx.y, __shfl_xor(mx.y, o));
    mx.z = fmaxf(mx.z, __shfl_xor(mx.z, o));
    mx.w = fmaxf(mx.w, __shfl_xor(mx.w, o));
  }
  float4 sm = make_float4(0.f, 0.f, 0.f, 0.f);
  for (int i = rs + lane; i < re; i += 64) {
    float4 a = ((const float4*)alpha_s)[i];
    sm.x += __expf(a.x - mx.x); sm.y += __expf(a.y - mx.y);
    sm.z += __expf(a.z - mx.z); sm.w += __expf(a.w - mx.w);
  }
#pragma unroll
  for (int o = 32; o >= 1; o >>= 1) {
    sm.x += __shfl_xor(sm.x, o); sm.y += __shfl_xor(sm.y, o);
    sm.z += __shfl_xor(sm.z, o); sm.w += __shfl_xor(sm.w, o);
  }
  int h = lane >> 4;
  float mxh = (h == 0) ? mx.x : (h == 1) ? mx.y : (h == 2) ? mx.z : mx.w;
  float smh = (h == 0) ? sm.x : (h == 1) ? sm.y : (h == 2) ? sm.z : sm.w;
  float rden = 1.f / (smh + SOFT_EPS);

  float ax = 0.f, ay = 0.f;
  for (int i = rs; i < re; ++i) {
    int s = es_src[i], et = es_et[i];
    float w = __expf(alpha_s[(size_t)i * 4 + h] - mxh) * rden;
    float2 xv = *(const float2*)(xw + ((size_t)et * N + s) * 128 + lane * 2);
    ax += w * xv.x; ay += w * xv.y;
  }

  if (concat) {
    float2 bv = *(const float2*)(bias + lane * 2);
    float vx = ax + bv.x, vy = ay + bv.y;
    vx = vx > 0.f ? vx : 0.f;
    vy = vy > 0.f ? vy : 0.f;
    *(float2*)(out + (size_t)d * 128 + lane * 2) = make_float2(vx, vy);
  } else {
#pragma unroll
    for (int o = 16; o <= 32; o <<= 1) {
      ax += __shfl_xor(ax, o);
      ay += __shfl_xor(ay, o);
    }
    if (lane < 16) {
      float2 bv = *(const float2*)(bias + lane * 2);
      *(float2*)(out + (size_t)d * 32 + lane * 2) =
          make_float2(0.25f * ax + bv.x, 0.25f * ay + bv.y);
    }
  }
}

extern "C" void kernel_launch(void* const* d_in, const int* in_sizes, int n_in,
                              void* d_out, int out_size, void* d_ws, size_t ws_size,
                              hipStream_t stream) {
  const float* x   = (const float*)d_in[0];
  const int*   ei  = (const int*)d_in[1];
  const float* ea  = (const float*)d_in[2];
  const int*   etp = (const int*)d_in[3];
  const float* w1  = (const float*)d_in[4];
  const float* q1  = (const float*)d_in[5];
  const float* k1  = (const float*)d_in[6];
  const float* e1  = (const float*)d_in[7];
  const float* le1 = (const float*)d_in[8];
  const float* b1  = (const float*)d_in[9];
  const float* w3  = (const float*)d_in[10];
  const float* q3  = (const float*)d_in[11];
  const float* k3  = (const float*)d_in[12];
  const float* e3  = (const float*)d_in[13];
  const float* le3 = (const float*)d_in[14];
  const float* b3  = (const float*)d_in[15];
  const int N = in_sizes[0] / 128;
  const int E = in_sizes[3];
  const int* srcp = ei;
  const int* dstp = ei + E;

  float* ws   = (float*)d_ws;
  float* xw   = ws;                                  // 4*N*128
  float* qn   = xw + (size_t)4 * N * 128;            // 4*N*4
  float* kn   = qn + (size_t)4 * N * 4;              // 4*N*4
  float* ekb  = kn + (size_t)4 * N * 4;              // E*4
  float* alph = ekb + (size_t)E * 4;                 // E*4
  float* hbuf = alph + (size_t)E * 4;                // N*128
  float* leeb = hbuf + (size_t)N * 128;              // 128
  int* deg      = (int*)(leeb + 128);                // N
  int* rowst    = deg + N;                           // N+1
  int* cursor   = rowst + N + 1;                     // N
  int* es_src   = cursor + N;                        // E
  int* es_dst   = es_src + E;                        // E
  int* es_et    = es_dst + E;                        // E
  int* es_eid   = es_et + E;                         // E
  (void)ws_size; (void)n_in; (void)out_size;

  int pgx  = (N + 127) / 128;
  int qkb  = (4 * N + 63) / 64;
  int eb   = (E + 255) / 256;
  int nb4  = (N + 3) / 4;

  hipMemsetAsync(deg, 0, (size_t)N * sizeof(int), stream);
  hist_kernel<<<eb, 256, 0, stream>>>(dstp, deg, E);
  scan_kernel<<<1, 256, 0, stream>>>(deg, rowst, cursor, N);
  scatter_kernel<<<eb, 256, 0, stream>>>(srcp, dstp, etp, cursor,
                                         es_src, es_dst, es_et, es_eid, E);
  lee_kernel<<<1, 128, 0, stream>>>(le1, e1, le3, e3, leeb);

  for (int layer = 0; layer < 2; ++layer) {
    const float* xin = layer ? hbuf : x;
    const float* w   = layer ? w3 : w1;
    const float* q   = layer ? q3 : q1;
    const float* k   = layer ? k3 : k1;
    const float* leep = leeb + (layer ? 64 : 0);
    const float* bias = layer ? b3 : b1;
    float* outp = layer ? (float*)d_out : hbuf;

    proj_kernel<<<dim3(pgx, 4), 256, 0, stream>>>(xin, w, xw, N);
    qk_kernel<<<qkb, 256, 0, stream>>>(xw, q, k, qn, kn, 4 * N);
    ek_kernel<<<eb, 256, 0, stream>>>(ea, leep, ekb, E);
    alpha_kernel<<<eb, 256, 0, stream>>>(es_src, es_dst, es_et, es_eid,
                                         qn, kn, ekb, alph, E, N);
    agg_kernel<<<nb4, 256, 0, stream>>>(es_src, es_et, rowst, alph, xw,
                                        bias, outp, N, layer == 0 ? 1 : 0);
  }
}

// Round 4
// 747.023 us; speedup vs baseline: 5.0176x; 1.1499x over previous
//
#include <hip/hip_runtime.h>

// RGATNetwork: 2x RGATConv (R=4, H=4, C=32, HC=128, F_E=16) on N=50k nodes, E=800k edges.
// R4: single-block scan_kernel (125 us, latency-bound) replaced by a 3-kernel
// hierarchical scan (chunk reduce -> block-sum scan -> chunk scan+offset).
// Rest unchanged from R3.

#define NEG_SLOPE 0.2f
#define SOFT_EPS 1e-16f

// lee[f,h] = sum_o le[f,o]*e[o,h]  for both layers (t<64: layer1, t>=64: layer3)
__global__ void lee_kernel(const float* __restrict__ le1, const float* __restrict__ e1,
                           const float* __restrict__ le3, const float* __restrict__ e3,
                           float* __restrict__ lee) {
  int t = threadIdx.x;
  const float* le = (t < 64) ? le1 : le3;
  const float* ee = (t < 64) ? e1 : e3;
  int u = t & 63, f = u >> 2, h = u & 3;
  float acc = 0.f;
  for (int o = 0; o < 128; ++o) acc += le[f * 128 + o] * ee[o * 4 + h];
  lee[t] = acc;
}

// ---- CSR build (once per call) ----
__global__ __launch_bounds__(256) void hist_kernel(const int* __restrict__ dst,
                                                   int* __restrict__ deg, int E) {
  int e = blockIdx.x * 256 + threadIdx.x;
  if (e < E) atomicAdd(&deg[dst[e]], 1);
}

// A: block b sums deg[b*1024 .. +1024) -> bsum[b]
__global__ __launch_bounds__(256) void scanA_kernel(const int* __restrict__ deg,
                                                    int* __restrict__ bsum, int N) {
  int b = blockIdx.x, t = threadIdx.x;
  int base = b * 1024 + t * 4;
  int s = 0;
#pragma unroll
  for (int j = 0; j < 4; ++j) {
    int i = base + j;
    if (i < N) s += deg[i];
  }
#pragma unroll
  for (int o = 1; o < 64; o <<= 1) s += __shfl_xor(s, o);
  __shared__ int wsum[4];
  if ((t & 63) == 0) wsum[t >> 6] = s;
  __syncthreads();
  if (t == 0) bsum[b] = wsum[0] + wsum[1] + wsum[2] + wsum[3];
}

// B: exclusive scan of bsum[0..nb) (nb<=256) -> boff; row_start[N]=total
__global__ __launch_bounds__(256) void scanB_kernel(const int* __restrict__ bsum,
                                                    int* __restrict__ boff,
                                                    int* __restrict__ row_start,
                                                    int nb, int N) {
  int t = threadIdx.x;
  int v = (t < nb) ? bsum[t] : 0;
  int inc = v;
#pragma unroll
  for (int o = 1; o < 64; o <<= 1) {
    int u = __shfl_up(inc, o);
    if ((t & 63) >= o) inc += u;
  }
  __shared__ int wt[4];
  if ((t & 63) == 63) wt[t >> 6] = inc;
  __syncthreads();
  int add = 0;
  for (int wv = 0; wv < (t >> 6); ++wv) add += wt[wv];
  inc += add;
  if (t < nb) boff[t] = inc - v;
  if (t == 255) row_start[N] = inc;  // zeros beyond nb don't change the total
}

// C: in-block exclusive scan of each 1024-chunk + block offset -> row_start, cursor
__global__ __launch_bounds__(256) void scanC_kernel(const int* __restrict__ deg,
                                                    const int* __restrict__ boff,
                                                    int* __restrict__ row_start,
                                                    int* __restrict__ cursor, int N) {
  int b = blockIdx.x, t = threadIdx.x;
  int base = b * 1024 + t * 4;
  int d[4];
  int s = 0;
#pragma unroll
  for (int j = 0; j < 4; ++j) {
    int i = base + j;
    d[j] = (i < N) ? deg[i] : 0;
    s += d[j];
  }
  int inc = s;
#pragma unroll
  for (int o = 1; o < 64; o <<= 1) {
    int u = __shfl_up(inc, o);
    if ((t & 63) >= o) inc += u;
  }
  __shared__ int wt[4];
  if ((t & 63) == 63) wt[t >> 6] = inc;
  __syncthreads();
  int add = boff[b];
  for (int wv = 0; wv < (t >> 6); ++wv) add += wt[wv];
  int off = add + inc - s;
#pragma unroll
  for (int j = 0; j < 4; ++j) {
    int i = base + j;
    if (i < N) {
      row_start[i] = off;
      cursor[i] = off;
      off += d[j];
    }
  }
}

__global__ __launch_bounds__(256) void scatter_kernel(
    const int* __restrict__ src, const int* __restrict__ dst, const int* __restrict__ et,
    int* __restrict__ cursor, int* __restrict__ es_src, int* __restrict__ es_dst,
    int* __restrict__ es_et, int* __restrict__ es_eid, int E) {
  int e = blockIdx.x * 256 + threadIdx.x;
  if (e >= E) return;
  int d = dst[e];
  int pos = atomicAdd(&cursor[d], 1);
  es_src[pos] = src[e];
  es_dst[pos] = d;
  es_et[pos] = et[e];
  es_eid[pos] = e;
}

// ---- proj: xw[r,n,:] = xin[n,:] @ w[r,:,:] ----
// grid (ceil(N/128), R), block 256. 128x128 tile, BK=32, 8x8 per thread.
#define SX_STRIDE 36
__global__ __launch_bounds__(256) void proj_kernel(const float* __restrict__ xin,
                                                   const float* __restrict__ w,
                                                   float* __restrict__ xw, int N) {
  __shared__ float sx[128 * SX_STRIDE];
  __shared__ float sw[32 * 128];
  int r = blockIdx.y;
  int nb = blockIdx.x * 128;
  int t = threadIdx.x;
  int tn = t >> 4;
  int to = t & 15;
  const float* wg = w + (size_t)r * (128 * 128);

  float acc[8][8];
#pragma unroll
  for (int j = 0; j < 8; ++j)
#pragma unroll
    for (int i = 0; i < 8; ++i) acc[j][i] = 0.f;

  for (int kc = 0; kc < 4; ++kc) {
    int k0 = kc * 32;
#pragma unroll
    for (int it = 0; it < 4; ++it) {
      int i = it * 256 + t;
      int n = i >> 3, f4 = i & 7;
      int ng = nb + n;
      float4 v = make_float4(0.f, 0.f, 0.f, 0.f);
      if (ng < N) v = *(const float4*)(xin + (size_t)ng * 128 + k0 + f4 * 4);
      *(float4*)(sx + n * SX_STRIDE + f4 * 4) = v;
    }
#pragma unroll
    for (int it = 0; it < 4; ++it) {
      int i = it * 256 + t;
      int f = i >> 5, o4 = i & 31;
      *(float4*)(sw + f * 128 + o4 * 4) =
          *(const float4*)(wg + (size_t)(k0 + f) * 128 + o4 * 4);
    }
    __syncthreads();

#pragma unroll
    for (int f4 = 0; f4 < 8; ++f4) {
      float4 xf[8];
#pragma unroll
      for (int j = 0; j < 8; ++j)
        xf[j] = *(const float4*)(sx + (tn + 16 * j) * SX_STRIDE + f4 * 4);
#pragma unroll
      for (int ff = 0; ff < 4; ++ff) {
        float4 wa = *(const float4*)(sw + (f4 * 4 + ff) * 128 + to * 4);
        float4 wb = *(const float4*)(sw + (f4 * 4 + ff) * 128 + 64 + to * 4);
#pragma unroll
        for (int j = 0; j < 8; ++j) {
          float xv = (ff == 0) ? xf[j].x : (ff == 1) ? xf[j].y : (ff == 2) ? xf[j].z : xf[j].w;
          acc[j][0] += xv * wa.x; acc[j][1] += xv * wa.y;
          acc[j][2] += xv * wa.z; acc[j][3] += xv * wa.w;
          acc[j][4] += xv * wb.x; acc[j][5] += xv * wb.y;
          acc[j][6] += xv * wb.z; acc[j][7] += xv * wb.w;
        }
      }
    }
    __syncthreads();
  }

#pragma unroll
  for (int j = 0; j < 8; ++j) {
    int n = nb + tn + 16 * j;
    if (n < N) {
      float* dstp = xw + ((size_t)r * N + n) * 128;
      *(float4*)(dstp + to * 4) = make_float4(acc[j][0], acc[j][1], acc[j][2], acc[j][3]);
      *(float4*)(dstp + 64 + to * 4) = make_float4(acc[j][4], acc[j][5], acc[j][6], acc[j][7]);
    }
  }
}

// qn[row,h], kn[row,h] for row in [0, R*N): 64 rows/block, 4 threads/row
__global__ __launch_bounds__(256) void qk_kernel(const float* __restrict__ xw,
                                                 const float* __restrict__ q,
                                                 const float* __restrict__ k,
                                                 float* __restrict__ qn,
                                                 float* __restrict__ kn, int total) {
  __shared__ float sx[64 * 132];
  __shared__ float sq[512];
  __shared__ float sk[512];
  int rb = blockIdx.x * 64;
  int t = threadIdx.x;
  if (t < 128) ((float4*)sq)[t] = ((const float4*)q)[t];
  else if (t < 256) ((float4*)sk)[t - 128] = ((const float4*)k)[t - 128];
  int nrow = total - rb; if (nrow > 64) nrow = 64;
  const float4* s4 = (const float4*)(xw + (size_t)rb * 128);
  for (int i = t; i < nrow * 32; i += 256) {
    ((float4*)sx)[(i >> 5) * 33 + (i & 31)] = s4[i];
  }
  __syncthreads();
  int rl = t >> 2, l = t & 3;
  float aq[4] = {0, 0, 0, 0}, ak[4] = {0, 0, 0, 0};
  for (int i = 0; i < 32; ++i) {
    int o = l + 4 * i;
    float xv = sx[rl * 132 + o];
#pragma unroll
    for (int h = 0; h < 4; ++h) {
      aq[h] += xv * sq[o * 4 + h];
      ak[h] += xv * sk[o * 4 + h];
    }
  }
#pragma unroll
  for (int h = 0; h < 4; ++h) {
    aq[h] += __shfl_xor(aq[h], 1); aq[h] += __shfl_xor(aq[h], 2);
    ak[h] += __shfl_xor(ak[h], 1); ak[h] += __shfl_xor(ak[h], 2);
  }
  int row = rb + rl;
  if (l == 0 && row < total) {
    *(float4*)(qn + (size_t)row * 4) = make_float4(aq[0], aq[1], aq[2], aq[3]);
    *(float4*)(kn + (size_t)row * 4) = make_float4(ak[0], ak[1], ak[2], ak[3]);
  }
}

// ek[e,h] = sum_{f<16} ea[e,f]*lee[f,h]
__global__ __launch_bounds__(256) void ek_kernel(const float* __restrict__ ea,
                                                 const float* __restrict__ lee,
                                                 float* __restrict__ ek, int E) {
  __shared__ float sl[64];
  if (threadIdx.x < 64) sl[threadIdx.x] = lee[threadIdx.x];
  __syncthreads();
  int e = blockIdx.x * 256 + threadIdx.x;
  if (e >= E) return;
  const float4* a4 = (const float4*)(ea + (size_t)e * 16);
  float acc[4] = {0, 0, 0, 0};
#pragma unroll
  for (int i = 0; i < 4; ++i) {
    float4 v = a4[i];
    int f = i * 4;
#pragma unroll
    for (int h = 0; h < 4; ++h) {
      acc[h] += v.x * sl[f * 4 + h] + v.y * sl[(f + 1) * 4 + h] +
                v.z * sl[(f + 2) * 4 + h] + v.w * sl[(f + 3) * 4 + h];
    }
  }
  *(float4*)(ek + (size_t)e * 4) = make_float4(acc[0], acc[1], acc[2], acc[3]);
}

// alpha in dst-sorted order
__global__ __launch_bounds__(256) void alpha_kernel(
    const int* __restrict__ es_src, const int* __restrict__ es_dst,
    const int* __restrict__ es_et, const int* __restrict__ es_eid,
    const float* __restrict__ qn, const float* __restrict__ kn,
    const float* __restrict__ ek, float* __restrict__ alpha_s, int E, int N) {
  int i = blockIdx.x * 256 + threadIdx.x;
  if (i >= E) return;
  int s = es_src[i], d = es_dst[i], et = es_et[i], e = es_eid[i];
  float4 qv = *(const float4*)(qn + ((size_t)et * N + d) * 4);
  float4 kv = *(const float4*)(kn + ((size_t)et * N + s) * 4);
  float4 ev = *(const float4*)(ek + (size_t)e * 4);
  float a0 = qv.x + kv.x + ev.x, a1 = qv.y + kv.y + ev.y;
  float a2 = qv.z + kv.z + ev.z, a3 = qv.w + kv.w + ev.w;
  a0 = a0 > 0.f ? a0 : NEG_SLOPE * a0;
  a1 = a1 > 0.f ? a1 : NEG_SLOPE * a1;
  a2 = a2 > 0.f ? a2 : NEG_SLOPE * a2;
  a3 = a3 > 0.f ? a3 : NEG_SLOPE * a3;
  *(float4*)(alpha_s + (size_t)i * 4) = make_float4(a0, a1, a2, a3);
}

// fused softmax + gather-aggregate + epilogue. One wave (64 lanes) per dst node.
__global__ __launch_bounds__(256) void agg_kernel(
    const int* __restrict__ es_src, const int* __restrict__ es_et,
    const int* __restrict__ row_start, const float* __restrict__ alpha_s,
    const float* __restrict__ xw, const float* __restrict__ bias,
    float* __restrict__ out, int N, int concat) {
  int d = blockIdx.x * 4 + (threadIdx.x >> 6);
  if (d >= N) return;
  int lane = threadIdx.x & 63;
  int rs = row_start[d], re = row_start[d + 1];

  float4 mx = make_float4(-1e30f, -1e30f, -1e30f, -1e30f);
  for (int i = rs + lane; i < re; i += 64) {
    float4 a = ((const float4*)alpha_s)[i];
    mx.x = fmaxf(mx.x, a.x); mx.y = fmaxf(mx.y, a.y);
    mx.z = fmaxf(mx.z, a.z); mx.w = fmaxf(mx.w, a.w);
  }
#pragma unroll
  for (int o = 32; o >= 1; o >>= 1) {
    mx.x = fmaxf(mx.x, __shfl_xor(mx.x, o));
    mx.y = fmaxf(mx.y, __shfl_xor(mx.y, o));
    mx.z = fmaxf(mx.z, __shfl_xor(mx.z, o));
    mx.w = fmaxf(mx.w, __shfl_xor(mx.w, o));
  }
  float4 sm = make_float4(0.f, 0.f, 0.f, 0.f);
  for (int i = rs + lane; i < re; i += 64) {
    float4 a = ((const float4*)alpha_s)[i];
    sm.x += __expf(a.x - mx.x); sm.y += __expf(a.y - mx.y);
    sm.z += __expf(a.z - mx.z); sm.w += __expf(a.w - mx.w);
  }
#pragma unroll
  for (int o = 32; o >= 1; o >>= 1) {
    sm.x += __shfl_xor(sm.x, o); sm.y += __shfl_xor(sm.y, o);
    sm.z += __shfl_xor(sm.z, o); sm.w += __shfl_xor(sm.w, o);
  }
  int h = lane >> 4;
  float mxh = (h == 0) ? mx.x : (h == 1) ? mx.y : (h == 2) ? mx.z : mx.w;
  float smh = (h == 0) ? sm.x : (h == 1) ? sm.y : (h == 2) ? sm.z : sm.w;
  float rden = 1.f / (smh + SOFT_EPS);

  float ax = 0.f, ay = 0.f;
  for (int i = rs; i < re; ++i) {
    int s = es_src[i], et = es_et[i];
    float w = __expf(alpha_s[(size_t)i * 4 + h] - mxh) * rden;
    float2 xv = *(const float2*)(xw + ((size_t)et * N + s) * 128 + lane * 2);
    ax += w * xv.x; ay += w * xv.y;
  }

  if (concat) {
    float2 bv = *(const float2*)(bias + lane * 2);
    float vx = ax + bv.x, vy = ay + bv.y;
    vx = vx > 0.f ? vx : 0.f;
    vy = vy > 0.f ? vy : 0.f;
    *(float2*)(out + (size_t)d * 128 + lane * 2) = make_float2(vx, vy);
  } else {
#pragma unroll
    for (int o = 16; o <= 32; o <<= 1) {
      ax += __shfl_xor(ax, o);
      ay += __shfl_xor(ay, o);
    }
    if (lane < 16) {
      float2 bv = *(const float2*)(bias + lane * 2);
      *(float2*)(out + (size_t)d * 32 + lane * 2) =
          make_float2(0.25f * ax + bv.x, 0.25f * ay + bv.y);
    }
  }
}

extern "C" void kernel_launch(void* const* d_in, const int* in_sizes, int n_in,
                              void* d_out, int out_size, void* d_ws, size_t ws_size,
                              hipStream_t stream) {
  const float* x   = (const float*)d_in[0];
  const int*   ei  = (const int*)d_in[1];
  const float* ea  = (const float*)d_in[2];
  const int*   etp = (const int*)d_in[3];
  const float* w1  = (const float*)d_in[4];
  const float* q1  = (const float*)d_in[5];
  const float* k1  = (const float*)d_in[6];
  const float* e1  = (const float*)d_in[7];
  const float* le1 = (const float*)d_in[8];
  const float* b1  = (const float*)d_in[9];
  const float* w3  = (const float*)d_in[10];
  const float* q3  = (const float*)d_in[11];
  const float* k3  = (const float*)d_in[12];
  const float* e3  = (const float*)d_in[13];
  const float* le3 = (const float*)d_in[14];
  const float* b3  = (const float*)d_in[15];
  const int N = in_sizes[0] / 128;
  const int E = in_sizes[3];
  const int* srcp = ei;
  const int* dstp = ei + E;

  float* ws   = (float*)d_ws;
  float* xw   = ws;                                  // 4*N*128
  float* qn   = xw + (size_t)4 * N * 128;            // 4*N*4
  float* kn   = qn + (size_t)4 * N * 4;              // 4*N*4
  float* ekb  = kn + (size_t)4 * N * 4;              // E*4
  float* alph = ekb + (size_t)E * 4;                 // E*4
  float* hbuf = alph + (size_t)E * 4;                // N*128
  float* leeb = hbuf + (size_t)N * 128;              // 128
  int* deg      = (int*)(leeb + 128);                // N
  int* rowst    = deg + N;                           // N+1
  int* cursor   = rowst + N + 1;                     // N
  int* es_src   = cursor + N;                        // E
  int* es_dst   = es_src + E;                        // E
  int* es_et    = es_dst + E;                        // E
  int* es_eid   = es_et + E;                         // E
  int* bsum     = es_eid + E;                        // 256
  int* boff     = bsum + 256;                        // 256
  (void)ws_size; (void)n_in; (void)out_size;

  int pgx  = (N + 127) / 128;
  int qkb  = (4 * N + 63) / 64;
  int eb   = (E + 255) / 256;
  int nb4  = (N + 3) / 4;
  int nbs  = (N + 1023) / 1024;  // scan blocks (<=256 for N<=262144)

  hipMemsetAsync(deg, 0, (size_t)N * sizeof(int), stream);
  hist_kernel<<<eb, 256, 0, stream>>>(dstp, deg, E);
  scanA_kernel<<<nbs, 256, 0, stream>>>(deg, bsum, N);
  scanB_kernel<<<1, 256, 0, stream>>>(bsum, boff, rowst, nbs, N);
  scanC_kernel<<<nbs, 256, 0, stream>>>(deg, boff, rowst, cursor, N);
  scatter_kernel<<<eb, 256, 0, stream>>>(srcp, dstp, etp, cursor,
                                         es_src, es_dst, es_et, es_eid, E);
  lee_kernel<<<1, 128, 0, stream>>>(le1, e1, le3, e3, leeb);

  for (int layer = 0; layer < 2; ++layer) {
    const float* xin = layer ? hbuf : x;
    const float* w   = layer ? w3 : w1;
    const float* q   = layer ? q3 : q1;
    const float* k   = layer ? k3 : k1;
    const float* leep = leeb + (layer ? 64 : 0);
    const float* bias = layer ? b3 : b1;
    float* outp = layer ? (float*)d_out : hbuf;

    proj_kernel<<<dim3(pgx, 4), 256, 0, stream>>>(xin, w, xw, N);
    qk_kernel<<<qkb, 256, 0, stream>>>(xw, q, k, qn, kn, 4 * N);
    ek_kernel<<<eb, 256, 0, stream>>>(ea, leep, ekb, E);
    alpha_kernel<<<eb, 256, 0, stream>>>(es_src, es_dst, es_et, es_eid,
                                         qn, kn, ekb, alph, E, N);
    agg_kernel<<<nb4, 256, 0, stream>>>(es_src, es_et, rowst, alph, xw,
                                        bias, outp, N, layer == 0 ? 1 : 0);
  }
}